// Round 9
// baseline (329.770 us; speedup 1.0000x reference)
//
#include <hip/hip_runtime.h>
#include <math.h>

#define B    256
#define NIN  1152
#define IND  8
#define NOUT 10
#define OUTD 16
#define M    160          // NOUT*OUTD
#define K    9216         // NIN*IND

typedef _Float16 h2 __attribute__((ext_vector_type(2)));
struct __align__(16) H8 { h2 h[4]; };   // 8 f16
struct __align__(8)  H4 { h2 h[2]; };   // 4 f16

#if defined(__has_builtin) && __has_builtin(__builtin_amdgcn_fdot2)
#define FDOT2(a, b, c) __builtin_amdgcn_fdot2((a), (b), (c), false)
#else
#define FDOT2(a, b, c) ((float)(a)[0] * (float)(b)[0] + (float)(a)[1] * (float)(b)[1] + (c))
#endif

// ================= k_w16: one-time W f32 -> f16 ==================
__global__ __launch_bounds__(256) void k_w16(const float* __restrict__ W,
                                             _Float16* __restrict__ Wh) {
    const int t = blockIdx.x * 256 + threadIdx.x;       // 368640 threads x4 elems
    const float4 f = *(const float4*)(W + (size_t)t * 4);
    H4 p;
    p.h[0] = h2{(_Float16)f.x, (_Float16)f.y};
    p.h[1] = h2{(_Float16)f.z, (_Float16)f.w};
    *(H4*)(Wh + (size_t)t * 4) = p;
}

// ================= k_su: s partials, W chunk staged in LDS as f16 ==================
// grid (CHUNKS=144, B/BT=8), 320 threads: mt = tid%40 (m-quad), bq = tid/40 (b-quad).
// Block stages Wh[8n][8i][160m] f16 (20.5 KB) once -> ~6 blocks/CU resident.
// Each thread: 4 batches x 4 cols, loops 8 n reading W via ds_read_b64 + cvt.
#define NCH    8
#define CHUNKS (NIN / NCH)   // 144
#define BT     32

template <int MODE>   // 0: c = 0.1 uniform (iter 0); 1: read cbuf (f16)
__global__ __launch_bounds__(320, 6) void k_su(const float* __restrict__ u,
                                               const _Float16* __restrict__ Wh,
                                               const _Float16* __restrict__ cbuf,
                                               _Float16* __restrict__ spart) {
    __shared__ _Float16 Wl[NCH * IND * M];   // 20480 B
    const int mt = threadIdx.x % 40;      // m-quad: columns mt*4 .. mt*4+3
    const int bq = threadIdx.x / 40;      // 0..7: batches bq*4 .. bq*4+3
    const int o  = mt >> 2;               // output capsule of this m-quad
    const int n0 = blockIdx.x * NCH;
    const int b0 = blockIdx.y * BT;
    const int bbase = b0 + bq * 4;

    // stage W chunk (f16): 1280 uint4, coalesced
    {
        const uint4* Wsrc = (const uint4*)(Wh + (size_t)n0 * IND * M);
        uint4* Wdst = (uint4*)Wl;
        for (int t = threadIdx.x; t < NCH * IND * M / 8; t += 320)
            Wdst[t] = Wsrc[t];
    }
    __syncthreads();

    float acc[4][4];
#pragma unroll
    for (int bs = 0; bs < 4; ++bs)
#pragma unroll
        for (int j = 0; j < 4; ++j) acc[bs][j] = 0.f;

    const float* up = u + (size_t)bbase * K + (size_t)n0 * IND;
    const _Float16* cp =
        MODE ? (cbuf + ((size_t)o * NIN + n0) * B + bbase) : nullptr;

#pragma unroll 2
    for (int ns = 0; ns < NCH; ++ns) {
        float c4[4];
        if (MODE) {
            const H4 ch = *(const H4*)(cp + (size_t)ns * B);   // 4 f16, 8B aligned
            c4[0] = (float)ch.h[0][0]; c4[1] = (float)ch.h[0][1];
            c4[2] = (float)ch.h[1][0]; c4[3] = (float)ch.h[1][1];
        } else {
            c4[0] = c4[1] = c4[2] = c4[3] = 0.1f;
        }
        float cu[4][8];
#pragma unroll
        for (int bs = 0; bs < 4; ++bs) {
            const float4 a0 = *(const float4*)(up + (size_t)bs * K + ns * IND);
            const float4 a1 = *(const float4*)(up + (size_t)bs * K + ns * IND + 4);
            cu[bs][0] = c4[bs] * a0.x; cu[bs][1] = c4[bs] * a0.y;
            cu[bs][2] = c4[bs] * a0.z; cu[bs][3] = c4[bs] * a0.w;
            cu[bs][4] = c4[bs] * a1.x; cu[bs][5] = c4[bs] * a1.y;
            cu[bs][6] = c4[bs] * a1.z; cu[bs][7] = c4[bs] * a1.w;
        }
#pragma unroll
        for (int i = 0; i < IND; ++i) {
            const H4 wh4 = *(const H4*)(Wl + (ns * IND + i) * M + mt * 4);  // ds_read_b64
            const float wx = (float)wh4.h[0][0], wy = (float)wh4.h[0][1];
            const float wz = (float)wh4.h[1][0], ww = (float)wh4.h[1][1];
#pragma unroll
            for (int bs = 0; bs < 4; ++bs) {
                acc[bs][0] = fmaf(cu[bs][i], wx, acc[bs][0]);
                acc[bs][1] = fmaf(cu[bs][i], wy, acc[bs][1]);
                acc[bs][2] = fmaf(cu[bs][i], wz, acc[bs][2]);
                acc[bs][3] = fmaf(cu[bs][i], ww, acc[bs][3]);
            }
        }
    }
    // store f16 partials: [chunk][b][m]
    _Float16* sp = spart + ((size_t)blockIdx.x * B + bbase) * M + mt * 4;
#pragma unroll
    for (int bs = 0; bs < 4; ++bs) {
        H4 p;
        p.h[0] = h2{(_Float16)acc[bs][0], (_Float16)acc[bs][1]};
        p.h[1] = h2{(_Float16)acc[bs][2], (_Float16)acc[bs][3]};
        *(H4*)(sp + (size_t)bs * M) = p;
    }
}

// ================= k_squash: reduce CHUNKS f16 partials + squash ==================
// grid 640 x 64, thread per output element (b,m). OUT16=1 -> f16 [b][160]; else f32.
template <int OUT16>
__global__ __launch_bounds__(64) void k_squash(const _Float16* __restrict__ spart,
                                               void* __restrict__ dstv) {
    const int gid = blockIdx.x * 64 + threadIdx.x;   // 0..40959, = b*160+m
    float s = 0.f;
#pragma unroll 16
    for (int ch = 0; ch < CHUNKS; ++ch) s += (float)spart[(size_t)ch * B * M + gid];
    float ss = s * s;
    ss += __shfl_xor(ss, 1);
    ss += __shfl_xor(ss, 2);
    ss += __shfl_xor(ss, 4);
    ss += __shfl_xor(ss, 8);          // sum over the 16 d-lanes (160 % 16 == 0)
    const float v = s * sqrtf(ss) / (1.f + ss);
    if (OUT16) ((_Float16*)dstv)[gid] = (_Float16)v;
    else       ((float*)dstv)[gid]    = v;
}

// ================= k_a: a = uhat . v ; b += a ; c = softmax(b) ==================
// grid (NIN/NA, B/64), 256 threads: lane = batch, wave = n (4 n per block).
// u staged to LDS (f32, stride 33); v16 rows staged to LDS (stride 164 ushorts);
// W in f16, wave-uniform dwordx4 broadcast; inner dot via v_dot2_f32_f16.
#define NA 4

template <int FIRST>
__global__ __launch_bounds__(256, 5) void k_a(const float* __restrict__ u,
                                              const _Float16* __restrict__ Wh,
                                              const _Float16* __restrict__ v16,
                                              _Float16* __restrict__ blog,
                                              _Float16* __restrict__ cbuf) {
    __shared__ float  lds_u[64 * 33];     // 8448 B
    __shared__ ushort lds_v[64 * 164];    // 20992 B
    const int bb = threadIdx.x & 63;
    const int ng = threadIdx.x >> 6;            // 0..3, wave-uniform
    const int n0 = blockIdx.x * NA;
    const int n  = n0 + ng;
    const int b0 = blockIdx.y * 64;
    const int gb = b0 + bb;

    // stage u[b0..b0+63][n0*8 .. n0*8+31]: 512 float4, coalesced
    for (int t = threadIdx.x; t < 512; t += 256) {
        const int r = t >> 3, c = t & 7;
        const float4 q = *(const float4*)(u + (size_t)(b0 + r) * K + (size_t)n0 * IND + c * 4);
        float* dst = lds_u + r * 33 + c * 4;
        dst[0] = q.x; dst[1] = q.y; dst[2] = q.z; dst[3] = q.w;
    }
    // stage v16 rows [b0..b0+63][160] f16: 64 x 40 8B-segments, coalesced
    {
        const _Float16* vsrc = v16 + (size_t)b0 * M;
        for (int t = threadIdx.x; t < 64 * 40; t += 256) {
            const int r = t / 40, s = t % 40;
            const uint2 q = *(const uint2*)(vsrc + (size_t)r * M + s * 4);
            *(uint2*)(lds_v + r * 164 + s * 4) = q;
        }
    }
    __syncthreads();

    float uu[IND];
#pragma unroll
    for (int i = 0; i < IND; ++i) uu[i] = lds_u[bb * 33 + ng * IND + i];

    const _Float16* Wn = Wh + (size_t)n * (IND * M);

    float a[NOUT];
#pragma unroll
    for (int o = 0; o < NOUT; ++o) {
        const ushort* vb = lds_v + bb * 164 + o * OUTD;
        const H4 v0 = *(const H4*)(vb);
        const H4 v1 = *(const H4*)(vb + 4);
        const H4 v2 = *(const H4*)(vb + 8);
        const H4 v3 = *(const H4*)(vb + 12);
        float acc = 0.f;
#pragma unroll
        for (int i = 0; i < IND; ++i) {
            const H8* wp = (const H8*)(Wn + i * M + o * OUTD);   // wave-uniform
            const H8 w0 = wp[0];
            const H8 w1 = wp[1];
            float wv = 0.f;
            wv = FDOT2(w0.h[0], v0.h[0], wv);
            wv = FDOT2(w0.h[1], v0.h[1], wv);
            wv = FDOT2(w0.h[2], v1.h[0], wv);
            wv = FDOT2(w0.h[3], v1.h[1], wv);
            wv = FDOT2(w1.h[0], v2.h[0], wv);
            wv = FDOT2(w1.h[1], v2.h[1], wv);
            wv = FDOT2(w1.h[2], v3.h[0], wv);
            wv = FDOT2(w1.h[3], v3.h[1], wv);
            acc = fmaf(uu[i], wv, acc);
        }
        a[o] = acc;
    }

    float bl[NOUT];
    _Float16* bp = blog + (size_t)n * NOUT * B + gb;   // [n][o][b], coalesced per o
    if (FIRST) {
#pragma unroll
        for (int o = 0; o < NOUT; ++o) { bl[o] = a[o]; bp[(size_t)o * B] = (_Float16)a[o]; }
    } else {
#pragma unroll
        for (int o = 0; o < NOUT; ++o) bl[o] = (float)bp[(size_t)o * B] + a[o];
    }
    float mx = bl[0];
#pragma unroll
    for (int o = 1; o < NOUT; ++o) mx = fmaxf(mx, bl[o]);
    float e[NOUT], sum = 0.f;
#pragma unroll
    for (int o = 0; o < NOUT; ++o) { e[o] = __expf(bl[o] - mx); sum += e[o]; }
    const float inv = 1.f / sum;
#pragma unroll
    for (int o = 0; o < NOUT; ++o)
        cbuf[((size_t)o * NIN + n) * B + gb] = (_Float16)(e[o] * inv);
}

// ================= launch ==================
extern "C" void kernel_launch(void* const* d_in, const int* in_sizes, int n_in,
                              void* d_out, int out_size, void* d_ws, size_t ws_size,
                              hipStream_t stream) {
    const float* u = (const float*)d_in[0];   // [256,1152,8]
    const float* W = (const float*)d_in[1];   // [1152,8,160]
    float* out = (float*)d_out;               // [256,10,16] f32

    char* ws = (char*)d_ws;
    _Float16* spart = (_Float16*)(ws);                      // 11,796,480 B
    _Float16* blog  = (_Float16*)(ws + 11796480);           //  5,898,240 B
    _Float16* cbuf  = (_Float16*)(ws + 17694720);           //  5,898,240 B
    _Float16* v16   = (_Float16*)(ws + 23592960);           //     81,920 B
    _Float16* Wh    = (_Float16*)(ws + 23674880);           //  2,949,120 B
    // total 26,624,000 B (~26.6 MB)

    const dim3 gs(CHUNKS, B / BT);           // (144, 8) = 1152 blocks
    const dim3 ga(NIN / NA, B / 64);         // (288, 4) = 1152 blocks

    // one-time W -> f16
    k_w16<<<1440, 256, 0, stream>>>(W, Wh);

    // iter 0: uniform c = 0.1
    k_su<0><<<gs, 320, 0, stream>>>(u, Wh, cbuf, spart);
    k_squash<1><<<640, 64, 0, stream>>>(spart, v16);
    // a0 -> blog=b1, c1
    k_a<1><<<ga, 256, 0, stream>>>(u, Wh, v16, blog, cbuf);
    // s1 -> v1
    k_su<1><<<gs, 320, 0, stream>>>(u, Wh, cbuf, spart);
    k_squash<1><<<640, 64, 0, stream>>>(spart, v16);
    // a1 -> b2 (in-register), c2
    k_a<0><<<ga, 256, 0, stream>>>(u, Wh, v16, blog, cbuf);
    // s2 -> v2 = output
    k_su<1><<<gs, 320, 0, stream>>>(u, Wh, cbuf, spart);
    k_squash<0><<<640, 64, 0, stream>>>(spart, out);
}

// Round 10
// 250.924 us; speedup vs baseline: 1.3142x; 1.3142x over previous
//
#include <hip/hip_runtime.h>
#include <math.h>

#define B    256
#define NIN  1152
#define IND  8
#define NOUT 10
#define OUTD 16
#define M    160          // NOUT*OUTD
#define K    9216         // NIN*IND

typedef _Float16 h2 __attribute__((ext_vector_type(2)));
struct __align__(16) H8 { h2 h[4]; };   // 8 f16
struct __align__(8)  H4 { h2 h[2]; };   // 4 f16

#if defined(__has_builtin) && __has_builtin(__builtin_amdgcn_fdot2)
#define FDOT2(a, b, c) __builtin_amdgcn_fdot2((a), (b), (c), false)
#else
#define FDOT2(a, b, c) ((float)(a)[0] * (float)(b)[0] + (float)(a)[1] * (float)(b)[1] + (c))
#endif

// ================= k_w16: one-time W f32 -> f16 ==================
__global__ __launch_bounds__(256) void k_w16(const float* __restrict__ W,
                                             _Float16* __restrict__ Wh) {
    const int t = blockIdx.x * 256 + threadIdx.x;       // 368640 threads x4 elems
    const float4 f = *(const float4*)(W + (size_t)t * 4);
    H4 p;
    p.h[0] = h2{(_Float16)f.x, (_Float16)f.y};
    p.h[1] = h2{(_Float16)f.z, (_Float16)f.w};
    *(H4*)(Wh + (size_t)t * 4) = p;
}

// ================= k_su: s partials, W chunk staged in LDS (f32) ==================
// grid (CHUNKS=288, B/BT=8), 320 threads: mt = tid%40 (m-quad), bq = tid/40 (b-quad).
// Block stages W[4n][8i][160m] f32 (20.5 KB) -> 6 blocks/CU resident (2x round 8).
// Each thread: 4 batches x 4 cols, full-unrolled 4-n loop, W via ds_read_b128.
#define NCH    4
#define CHUNKS (NIN / NCH)   // 288
#define BT     32

template <int MODE>   // 0: c = 0.1 uniform (iter 0); 1: read cbuf (f16)
__global__ __launch_bounds__(320, 8) void k_su(const float* __restrict__ u,
                                               const float* __restrict__ W,
                                               const _Float16* __restrict__ cbuf,
                                               _Float16* __restrict__ spart) {
    __shared__ float Wl[NCH * IND * M];   // 20480 B
    const int mt = threadIdx.x % 40;      // m-quad: columns mt*4 .. mt*4+3
    const int bq = threadIdx.x / 40;      // 0..7: batches bq*4 .. bq*4+3
    const int o  = mt >> 2;               // output capsule of this m-quad
    const int n0 = blockIdx.x * NCH;
    const int b0 = blockIdx.y * BT;
    const int bbase = b0 + bq * 4;

    // stage W chunk: 1280 float4, coalesced (4 per thread)
    {
        const float* Wsrc = W + (size_t)n0 * IND * M;
        for (int t = threadIdx.x; t < NCH * IND * M / 4; t += 320) {
            const float4 q = *(const float4*)(Wsrc + (size_t)t * 4);
            *(float4*)(Wl + t * 4) = q;
        }
    }
    __syncthreads();

    float acc[4][4];
#pragma unroll
    for (int bs = 0; bs < 4; ++bs)
#pragma unroll
        for (int j = 0; j < 4; ++j) acc[bs][j] = 0.f;

    const float* up = u + (size_t)bbase * K + (size_t)n0 * IND;
    const _Float16* cp =
        MODE ? (cbuf + ((size_t)o * NIN + n0) * B + bbase) : nullptr;

#pragma unroll
    for (int ns = 0; ns < NCH; ++ns) {
        float c4[4];
        if (MODE) {
            const H4 ch = *(const H4*)(cp + (size_t)ns * B);   // 4 f16, 8B aligned
            c4[0] = (float)ch.h[0][0]; c4[1] = (float)ch.h[0][1];
            c4[2] = (float)ch.h[1][0]; c4[3] = (float)ch.h[1][1];
        } else {
            c4[0] = c4[1] = c4[2] = c4[3] = 0.1f;
        }
        float cu[4][8];
#pragma unroll
        for (int bs = 0; bs < 4; ++bs) {
            const float4 a0 = *(const float4*)(up + (size_t)bs * K + ns * IND);
            const float4 a1 = *(const float4*)(up + (size_t)bs * K + ns * IND + 4);
            cu[bs][0] = c4[bs] * a0.x; cu[bs][1] = c4[bs] * a0.y;
            cu[bs][2] = c4[bs] * a0.z; cu[bs][3] = c4[bs] * a0.w;
            cu[bs][4] = c4[bs] * a1.x; cu[bs][5] = c4[bs] * a1.y;
            cu[bs][6] = c4[bs] * a1.z; cu[bs][7] = c4[bs] * a1.w;
        }
#pragma unroll
        for (int i = 0; i < IND; ++i) {
            const float4 w = *(const float4*)(Wl + (ns * IND + i) * M + mt * 4);
#pragma unroll
            for (int bs = 0; bs < 4; ++bs) {
                acc[bs][0] = fmaf(cu[bs][i], w.x, acc[bs][0]);
                acc[bs][1] = fmaf(cu[bs][i], w.y, acc[bs][1]);
                acc[bs][2] = fmaf(cu[bs][i], w.z, acc[bs][2]);
                acc[bs][3] = fmaf(cu[bs][i], w.w, acc[bs][3]);
            }
        }
    }
    // store f16 partials: [chunk][b][m]
    _Float16* sp = spart + ((size_t)blockIdx.x * B + bbase) * M + mt * 4;
#pragma unroll
    for (int bs = 0; bs < 4; ++bs) {
        H4 p;
        p.h[0] = h2{(_Float16)acc[bs][0], (_Float16)acc[bs][1]};
        p.h[1] = h2{(_Float16)acc[bs][2], (_Float16)acc[bs][3]};
        *(H4*)(sp + (size_t)bs * M) = p;
    }
}

// ================= k_squash: reduce CHUNKS f16 partials + squash ==================
// grid 640 x 64, thread per output element (b,m). OUT16=1 -> f16 [b][160]; else f32.
template <int OUT16>
__global__ __launch_bounds__(64) void k_squash(const _Float16* __restrict__ spart,
                                               void* __restrict__ dstv) {
    const int gid = blockIdx.x * 64 + threadIdx.x;   // 0..40959, = b*160+m
    float s = 0.f;
#pragma unroll 16
    for (int ch = 0; ch < CHUNKS; ++ch) s += (float)spart[(size_t)ch * B * M + gid];
    float ss = s * s;
    ss += __shfl_xor(ss, 1);
    ss += __shfl_xor(ss, 2);
    ss += __shfl_xor(ss, 4);
    ss += __shfl_xor(ss, 8);          // sum over the 16 d-lanes (160 % 16 == 0)
    const float v = s * sqrtf(ss) / (1.f + ss);
    if (OUT16) ((_Float16*)dstv)[gid] = (_Float16)v;
    else       ((float*)dstv)[gid]    = v;
}

// ================= k_a: a = uhat . v ; b += a ; c = softmax(b) ==================
// grid (NIN/NA, B/64), 256 threads: lane = batch, wave = n (4 n per block).
// u staged to LDS (f32, stride 33); v16 rows staged to LDS (stride 164 ushorts);
// W in f16, wave-uniform dwordx4 broadcast; inner dot via v_dot2_f32_f16.
#define NA 4

template <int FIRST>
__global__ __launch_bounds__(256, 5) void k_a(const float* __restrict__ u,
                                              const _Float16* __restrict__ Wh,
                                              const _Float16* __restrict__ v16,
                                              _Float16* __restrict__ blog,
                                              _Float16* __restrict__ cbuf) {
    __shared__ float  lds_u[64 * 33];     // 8448 B
    __shared__ ushort lds_v[64 * 164];    // 20992 B
    const int bb = threadIdx.x & 63;
    const int ng = threadIdx.x >> 6;            // 0..3, wave-uniform
    const int n0 = blockIdx.x * NA;
    const int n  = n0 + ng;
    const int b0 = blockIdx.y * 64;
    const int gb = b0 + bb;

    // stage u[b0..b0+63][n0*8 .. n0*8+31]: 512 float4, coalesced
    for (int t = threadIdx.x; t < 512; t += 256) {
        const int r = t >> 3, c = t & 7;
        const float4 q = *(const float4*)(u + (size_t)(b0 + r) * K + (size_t)n0 * IND + c * 4);
        float* dst = lds_u + r * 33 + c * 4;
        dst[0] = q.x; dst[1] = q.y; dst[2] = q.z; dst[3] = q.w;
    }
    // stage v16 rows [b0..b0+63][160] f16: 64 x 40 8B-segments, coalesced
    {
        const _Float16* vsrc = v16 + (size_t)b0 * M;
        for (int t = threadIdx.x; t < 64 * 40; t += 256) {
            const int r = t / 40, s = t % 40;
            const uint2 q = *(const uint2*)(vsrc + (size_t)r * M + s * 4);
            *(uint2*)(lds_v + r * 164 + s * 4) = q;
        }
    }
    __syncthreads();

    float uu[IND];
#pragma unroll
    for (int i = 0; i < IND; ++i) uu[i] = lds_u[bb * 33 + ng * IND + i];

    const _Float16* Wn = Wh + (size_t)n * (IND * M);

    float a[NOUT];
#pragma unroll
    for (int o = 0; o < NOUT; ++o) {
        const ushort* vb = lds_v + bb * 164 + o * OUTD;
        const H4 v0 = *(const H4*)(vb);
        const H4 v1 = *(const H4*)(vb + 4);
        const H4 v2 = *(const H4*)(vb + 8);
        const H4 v3 = *(const H4*)(vb + 12);
        float acc = 0.f;
#pragma unroll
        for (int i = 0; i < IND; ++i) {
            const H8* wp = (const H8*)(Wn + i * M + o * OUTD);   // wave-uniform
            const H8 w0 = wp[0];
            const H8 w1 = wp[1];
            float wv = 0.f;
            wv = FDOT2(w0.h[0], v0.h[0], wv);
            wv = FDOT2(w0.h[1], v0.h[1], wv);
            wv = FDOT2(w0.h[2], v1.h[0], wv);
            wv = FDOT2(w0.h[3], v1.h[1], wv);
            wv = FDOT2(w1.h[0], v2.h[0], wv);
            wv = FDOT2(w1.h[1], v2.h[1], wv);
            wv = FDOT2(w1.h[2], v3.h[0], wv);
            wv = FDOT2(w1.h[3], v3.h[1], wv);
            acc = fmaf(uu[i], wv, acc);
        }
        a[o] = acc;
    }

    float bl[NOUT];
    _Float16* bp = blog + (size_t)n * NOUT * B + gb;   // [n][o][b], coalesced per o
    if (FIRST) {
#pragma unroll
        for (int o = 0; o < NOUT; ++o) { bl[o] = a[o]; bp[(size_t)o * B] = (_Float16)a[o]; }
    } else {
#pragma unroll
        for (int o = 0; o < NOUT; ++o) bl[o] = (float)bp[(size_t)o * B] + a[o];
    }
    float mx = bl[0];
#pragma unroll
    for (int o = 1; o < NOUT; ++o) mx = fmaxf(mx, bl[o]);
    float e[NOUT], sum = 0.f;
#pragma unroll
    for (int o = 0; o < NOUT; ++o) { e[o] = __expf(bl[o] - mx); sum += e[o]; }
    const float inv = 1.f / sum;
#pragma unroll
    for (int o = 0; o < NOUT; ++o)
        cbuf[((size_t)o * NIN + n) * B + gb] = (_Float16)(e[o] * inv);
}

// ================= launch ==================
extern "C" void kernel_launch(void* const* d_in, const int* in_sizes, int n_in,
                              void* d_out, int out_size, void* d_ws, size_t ws_size,
                              hipStream_t stream) {
    const float* u = (const float*)d_in[0];   // [256,1152,8]
    const float* W = (const float*)d_in[1];   // [1152,8,160]
    float* out = (float*)d_out;               // [256,10,16] f32

    char* ws = (char*)d_ws;
    _Float16* spart = (_Float16*)(ws);                      // 23,592,960 B
    _Float16* blog  = (_Float16*)(ws + 23592960);           //  5,898,240 B
    _Float16* cbuf  = (_Float16*)(ws + 29491200);           //  5,898,240 B
    _Float16* v16   = (_Float16*)(ws + 35389440);           //     81,920 B
    _Float16* Wh    = (_Float16*)(ws + 35471360);           //  2,949,120 B
    // total 38,420,480 B (~38.4 MB)

    const dim3 gs(CHUNKS, B / BT);           // (288, 8) = 2304 blocks
    const dim3 ga(NIN / NA, B / 64);         // (288, 4) = 1152 blocks

    // one-time W -> f16 (for k_a)
    k_w16<<<1440, 256, 0, stream>>>(W, Wh);

    // iter 0: uniform c = 0.1
    k_su<0><<<gs, 320, 0, stream>>>(u, W, cbuf, spart);
    k_squash<1><<<640, 64, 0, stream>>>(spart, v16);
    // a0 -> blog=b1, c1
    k_a<1><<<ga, 256, 0, stream>>>(u, Wh, v16, blog, cbuf);
    // s1 -> v1
    k_su<1><<<gs, 320, 0, stream>>>(u, W, cbuf, spart);
    k_squash<1><<<640, 64, 0, stream>>>(spart, v16);
    // a1 -> b2 (in-register), c2
    k_a<0><<<ga, 256, 0, stream>>>(u, Wh, v16, blog, cbuf);
    // s2 -> v2 = output
    k_su<1><<<gs, 320, 0, stream>>>(u, W, cbuf, spart);
    k_squash<0><<<640, 64, 0, stream>>>(spart, out);
}

// Round 11
// 128.075 us; speedup vs baseline: 2.5748x; 1.9592x over previous
//
#include <hip/hip_runtime.h>
#include <math.h>

#define B    256
#define NIN  1152
#define IND  8
#define NOUT 10
#define OUTD 16
#define M    160          // NOUT*OUTD
#define K    9216         // NIN*IND

typedef _Float16 h2    __attribute__((ext_vector_type(2)));
typedef _Float16 f16x8 __attribute__((ext_vector_type(8)));
typedef float    f32x4 __attribute__((ext_vector_type(4)));
struct __align__(16) H8 { h2 h[4]; };   // 8 f16
struct __align__(8)  H4 { h2 h[2]; };   // 4 f16

#if defined(__has_builtin) && __has_builtin(__builtin_amdgcn_fdot2)
#define FDOT2(a, b, c) __builtin_amdgcn_fdot2((a), (b), (c), false)
#else
#define FDOT2(a, b, c) ((float)(a)[0] * (float)(b)[0] + (float)(a)[1] * (float)(b)[1] + (c))
#endif

// ================= prep: W f32 -> Wh f16 (same layout, for k_a) =================
__global__ __launch_bounds__(256) void k_w16(const float* __restrict__ W,
                                             _Float16* __restrict__ Wh) {
    const int t = blockIdx.x * 256 + threadIdx.x;
    const float4 f = *(const float4*)(W + (size_t)t * 4);
    H4 p;
    p.h[0] = h2{(_Float16)f.x, (_Float16)f.y};
    p.h[1] = h2{(_Float16)f.z, (_Float16)f.w};
    *(H4*)(Wh + (size_t)t * 4) = p;
}

// ================= prep: u f32 -> u16 f16 (same layout) =================
__global__ __launch_bounds__(256) void k_u16(const float* __restrict__ u,
                                             _Float16* __restrict__ u16) {
    const size_t t = (size_t)blockIdx.x * 256 + threadIdx.x;   // x4 elems
    const float4 f = *(const float4*)(u + t * 4);
    H4 p;
    p.h[0] = h2{(_Float16)f.x, (_Float16)f.y};
    p.h[1] = h2{(_Float16)f.z, (_Float16)f.w};
    *(H4*)(u16 + t * 4) = p;
}

// ================= prep: W -> Wt f16 [n][o][d][i] (MFMA B-fragment layout) =========
__global__ __launch_bounds__(256) void k_wt(const float* __restrict__ W,
                                            _Float16* __restrict__ Wt) {
    __shared__ float wl[IND * M];   // 5120 B
    const int n = blockIdx.x;
    const float* src = W + (size_t)n * IND * M;
    for (int t = threadIdx.x; t < IND * M / 4; t += 256)
        *(float4*)(wl + t * 4) = *(const float4*)(src + (size_t)t * 4);
    __syncthreads();
    const int t = threadIdx.x;
    if (t < 160) {
        const int o = t >> 4, d = t & 15;
        f16x8 out;
#pragma unroll
        for (int i = 0; i < IND; ++i) out[i] = (_Float16)wl[i * M + o * OUTD + d];
        *(f16x8*)(Wt + (((size_t)n * NOUT + o) * OUTD + d) * IND) = out;
    }
}

// ================= k_su: MFMA 16x16x32 f16 =================
// grid (16 btiles, 96 splits), 128 thr = 2 waves (wave w: o = w*5..w*5+4).
// Per n-group of 4: A[16b x 32k] = c*u (k=(q=lane>>4)*8+i), B = Wt frag, acc += A*B.
// C layout: col(d)=lane&15, row(b-local)=(lane>>4)*4+reg  [verified m89/m121].
#define NSPLIT 96
#define GPS    3      // n-groups (of 4 n) per split: 96*3*4 = 1152

template <int MODE>   // 0: c = 0.1 uniform; 1: read cbuf (f16)
__global__ __launch_bounds__(128, 4) void k_su(const _Float16* __restrict__ u16,
                                               const _Float16* __restrict__ Wt,
                                               const _Float16* __restrict__ cbuf,
                                               _Float16* __restrict__ spart) {
    const int lane  = threadIdx.x & 63;
    const int wv    = threadIdx.x >> 6;     // 0..1
    const int btile = blockIdx.x;           // 0..15
    const int split = blockIdx.y;           // 0..95
    const int bl    = lane & 15;            // A-row / b-local, B-col / d
    const int q     = lane >> 4;            // k-block = n offset within group
    const int b     = btile * 16 + bl;
    const int nbase = split * (GPS * 4);

    f32x4 acc[5];
#pragma unroll
    for (int j = 0; j < 5; ++j) acc[j] = f32x4{0.f, 0.f, 0.f, 0.f};

#pragma unroll
    for (int g = 0; g < GPS; ++g) {
        const int n = nbase + g * 4 + q;
        const f16x8 uf = *(const f16x8*)(u16 + ((size_t)b * NIN + n) * IND);
#pragma unroll
        for (int j = 0; j < 5; ++j) {
            const int o = wv * 5 + j;
            f16x8 a;
            if (MODE) {
                const _Float16 cv = cbuf[((size_t)o * NIN + n) * B + b];
#pragma unroll
                for (int i = 0; i < IND; ++i) a[i] = uf[i] * cv;
            } else {
                a = uf;
            }
            const f16x8 bf =
                *(const f16x8*)(Wt + (((size_t)n * NOUT + o) * OUTD + bl) * IND);
            acc[j] = __builtin_amdgcn_mfma_f32_16x16x32_f16(a, bf, acc[j], 0, 0, 0);
        }
    }

    // epilogue: D row = q*4+r (b-local), col = bl (d)
    const float scale = MODE ? 1.0f : 0.1f;
    _Float16* sp = spart + (size_t)split * B * M + ((size_t)btile * 16) * M;
#pragma unroll
    for (int r = 0; r < 4; ++r) {
        const int brow = q * 4 + r;
#pragma unroll
        for (int j = 0; j < 5; ++j) {
            const int o = wv * 5 + j;
            sp[(size_t)brow * M + o * OUTD + bl] = (_Float16)(acc[j][r] * scale);
        }
    }
}

// ================= k_squash: reduce NSPLIT f16 partials + squash ==================
template <int OUT16>
__global__ __launch_bounds__(64) void k_squash(const _Float16* __restrict__ spart,
                                               void* __restrict__ dstv) {
    const int gid = blockIdx.x * 64 + threadIdx.x;   // 0..40959, = b*160+m
    float s = 0.f;
#pragma unroll 16
    for (int ch = 0; ch < NSPLIT; ++ch) s += (float)spart[(size_t)ch * B * M + gid];
    float ss = s * s;
    ss += __shfl_xor(ss, 1);
    ss += __shfl_xor(ss, 2);
    ss += __shfl_xor(ss, 4);
    ss += __shfl_xor(ss, 8);          // sum over the 16 d-lanes (160 % 16 == 0)
    const float v = s * sqrtf(ss) / (1.f + ss);
    if (OUT16) ((_Float16*)dstv)[gid] = (_Float16)v;
    else       ((float*)dstv)[gid]    = v;
}

// ================= k_a: a = uhat . v ; b += a ; c = softmax(b) ==================
// (round-8 best-known form, unchanged)
#define NA 4

template <int FIRST>
__global__ __launch_bounds__(256, 5) void k_a(const float* __restrict__ u,
                                              const _Float16* __restrict__ Wh,
                                              const _Float16* __restrict__ v16,
                                              _Float16* __restrict__ blog,
                                              _Float16* __restrict__ cbuf) {
    __shared__ float  lds_u[64 * 33];     // 8448 B
    __shared__ ushort lds_v[64 * 164];    // 20992 B
    const int bb = threadIdx.x & 63;
    const int ng = threadIdx.x >> 6;            // 0..3, wave-uniform
    const int n0 = blockIdx.x * NA;
    const int n  = n0 + ng;
    const int b0 = blockIdx.y * 64;
    const int gb = b0 + bb;

    for (int t = threadIdx.x; t < 512; t += 256) {
        const int r = t >> 3, c = t & 7;
        const float4 q = *(const float4*)(u + (size_t)(b0 + r) * K + (size_t)n0 * IND + c * 4);
        float* dst = lds_u + r * 33 + c * 4;
        dst[0] = q.x; dst[1] = q.y; dst[2] = q.z; dst[3] = q.w;
    }
    {
        const _Float16* vsrc = v16 + (size_t)b0 * M;
        for (int t = threadIdx.x; t < 64 * 40; t += 256) {
            const int r = t / 40, s = t % 40;
            const uint2 q = *(const uint2*)(vsrc + (size_t)r * M + s * 4);
            *(uint2*)(lds_v + r * 164 + s * 4) = q;
        }
    }
    __syncthreads();

    float uu[IND];
#pragma unroll
    for (int i = 0; i < IND; ++i) uu[i] = lds_u[bb * 33 + ng * IND + i];

    const _Float16* Wn = Wh + (size_t)n * (IND * M);

    float a[NOUT];
#pragma unroll
    for (int o = 0; o < NOUT; ++o) {
        const ushort* vb = lds_v + bb * 164 + o * OUTD;
        const H4 v0 = *(const H4*)(vb);
        const H4 v1 = *(const H4*)(vb + 4);
        const H4 v2 = *(const H4*)(vb + 8);
        const H4 v3 = *(const H4*)(vb + 12);
        float acc = 0.f;
#pragma unroll
        for (int i = 0; i < IND; ++i) {
            const H8* wp = (const H8*)(Wn + i * M + o * OUTD);   // wave-uniform
            const H8 w0 = wp[0];
            const H8 w1 = wp[1];
            float wv = 0.f;
            wv = FDOT2(w0.h[0], v0.h[0], wv);
            wv = FDOT2(w0.h[1], v0.h[1], wv);
            wv = FDOT2(w0.h[2], v1.h[0], wv);
            wv = FDOT2(w0.h[3], v1.h[1], wv);
            wv = FDOT2(w1.h[0], v2.h[0], wv);
            wv = FDOT2(w1.h[1], v2.h[1], wv);
            wv = FDOT2(w1.h[2], v3.h[0], wv);
            wv = FDOT2(w1.h[3], v3.h[1], wv);
            acc = fmaf(uu[i], wv, acc);
        }
        a[o] = acc;
    }

    float bl[NOUT];
    _Float16* bp = blog + (size_t)n * NOUT * B + gb;   // [n][o][b], coalesced per o
    if (FIRST) {
#pragma unroll
        for (int o = 0; o < NOUT; ++o) { bl[o] = a[o]; bp[(size_t)o * B] = (_Float16)a[o]; }
    } else {
#pragma unroll
        for (int o = 0; o < NOUT; ++o) bl[o] = (float)bp[(size_t)o * B] + a[o];
    }
    float mx = bl[0];
#pragma unroll
    for (int o = 1; o < NOUT; ++o) mx = fmaxf(mx, bl[o]);
    float e[NOUT], sum = 0.f;
#pragma unroll
    for (int o = 0; o < NOUT; ++o) { e[o] = __expf(bl[o] - mx); sum += e[o]; }
    const float inv = 1.f / sum;
#pragma unroll
    for (int o = 0; o < NOUT; ++o)
        cbuf[((size_t)o * NIN + n) * B + gb] = (_Float16)(e[o] * inv);
}

// ================= launch ==================
extern "C" void kernel_launch(void* const* d_in, const int* in_sizes, int n_in,
                              void* d_out, int out_size, void* d_ws, size_t ws_size,
                              hipStream_t stream) {
    const float* u = (const float*)d_in[0];   // [256,1152,8]
    const float* W = (const float*)d_in[1];   // [1152,8,160]
    float* out = (float*)d_out;               // [256,10,16] f32

    char* ws = (char*)d_ws;
    _Float16* spart = (_Float16*)(ws);                      //  7,864,320 B
    _Float16* blog  = (_Float16*)(ws + 7864320);            //  5,898,240 B
    _Float16* cbuf  = (_Float16*)(ws + 13762560);           //  5,898,240 B
    _Float16* v16   = (_Float16*)(ws + 19660800);           //     81,920 B
    _Float16* Wh    = (_Float16*)(ws + 19742720);           //  2,949,120 B
    _Float16* Wt    = (_Float16*)(ws + 22691840);           //  2,949,120 B
    _Float16* u16   = (_Float16*)(ws + 25640960);           //  4,718,592 B
    // total 30,359,552 B (~30.4 MB)

    const dim3 gs(16, NSPLIT);               // (16, 96) = 1536 blocks, btile fastest
    const dim3 ga(NIN / NA, B / 64);         // (288, 4) = 1152 blocks

    // one-time preps
    k_w16<<<1440, 256, 0, stream>>>(W, Wh);
    k_wt<<<NIN, 256, 0, stream>>>(W, Wt);
    k_u16<<<2304, 256, 0, stream>>>(u, u16);

    // iter 0: uniform c = 0.1
    k_su<0><<<gs, 128, 0, stream>>>(u16, Wt, cbuf, spart);
    k_squash<1><<<640, 64, 0, stream>>>(spart, v16);
    // a0 -> blog=b1, c1
    k_a<1><<<ga, 256, 0, stream>>>(u, Wh, v16, blog, cbuf);
    // s1 -> v1
    k_su<1><<<gs, 128, 0, stream>>>(u16, Wt, cbuf, spart);
    k_squash<1><<<640, 64, 0, stream>>>(spart, v16);
    // a1 -> b2 (in-register), c2
    k_a<0><<<ga, 256, 0, stream>>>(u, Wh, v16, blog, cbuf);
    // s2 -> v2 = output
    k_su<1><<<gs, 128, 0, stream>>>(u16, Wt, cbuf, spart);
    k_squash<0><<<640, 64, 0, stream>>>(spart, out);
}